// Round 1
// baseline (1292.440 us; speedup 1.0000x reference)
//
#include <hip/hip_runtime.h>
#include <cstdint>
#include <cstddef>

#define SL 2048
#define BS 2
#define NH 32
#define HD 128
#define HS 4096
#define NTOK 4096  // BS*SL

typedef __attribute__((ext_vector_type(8))) short short8;
typedef __attribute__((ext_vector_type(4))) float f32x4;
typedef __attribute__((ext_vector_type(4))) unsigned short u16x4;
typedef __attribute__((ext_vector_type(8))) unsigned short u16x8;

static __device__ __forceinline__ unsigned short f2bf(float f) {
    unsigned int u = __builtin_bit_cast(unsigned int, f);
    u = u + 0x7FFFu + ((u >> 16) & 1u);   // RNE
    return (unsigned short)(u >> 16);
}
static __device__ __forceinline__ float bf2f(unsigned short h) {
    unsigned int u = ((unsigned int)h) << 16;
    return __builtin_bit_cast(float, u);
}

static __device__ __forceinline__ f32x4 mfma16(short8 a, short8 b, f32x4 c) {
    return __builtin_amdgcn_mfma_f32_16x16x32_bf16(a, b, c, 0, 0, 0);
}

static __device__ __forceinline__ void gload_lds16(const void* g, void* dst) {
    __builtin_amdgcn_global_load_lds(
        (const __attribute__((address_space(1))) unsigned int*)g,
        (__attribute__((address_space(3))) unsigned int*)dst,
        16, 0, 0);
}

// ---------------- fp32 -> bf16 convert (X) ----------------
__global__ void k_convert(const float* __restrict__ in, unsigned short* __restrict__ out, int n8) {
    int stride = gridDim.x * blockDim.x;
    for (int i = blockIdx.x * blockDim.x + threadIdx.x; i < n8; i += stride) {
        const f32x4* p = (const f32x4*)in + (size_t)i * 2;
        f32x4 a = p[0], b = p[1];
        u16x8 o;
        o[0] = f2bf(a[0]); o[1] = f2bf(a[1]); o[2] = f2bf(a[2]); o[3] = f2bf(a[3]);
        o[4] = f2bf(b[0]); o[5] = f2bf(b[1]); o[6] = f2bf(b[2]); o[7] = f2bf(b[3]);
        *((u16x8*)out + i) = o;
    }
}

// ---------------- fp32 W[k][n] -> bf16 Wt[n][k] ----------------
__global__ void k_transpose_w(const float* __restrict__ w, unsigned short* __restrict__ wt) {
    __shared__ float t[32][33];
    int r0 = blockIdx.y << 5, c0 = blockIdx.x << 5;
    int tr = threadIdx.x >> 3;
    int tc = (threadIdx.x & 7) << 2;
    f32x4 v = *(const f32x4*)(w + (size_t)(r0 + tr) * HS + c0 + tc);
    t[tr][tc + 0] = v[0]; t[tr][tc + 1] = v[1]; t[tr][tc + 2] = v[2]; t[tr][tc + 3] = v[3];
    __syncthreads();
    u16x4 o;
    o[0] = f2bf(t[tc + 0][tr]); o[1] = f2bf(t[tc + 1][tr]);
    o[2] = f2bf(t[tc + 2][tr]); o[3] = f2bf(t[tc + 3][tr]);
    *(u16x4*)(wt + (size_t)(c0 + tr) * HS + r0 + tc) = o;
}

// ---------------- bf16 GEMM: C[M][N] = A[M][K] * Bt[N][K]^T ----------------
template <typename OutT>
__global__ __launch_bounds__(256) void k_gemm(
    const unsigned short* __restrict__ A,
    const unsigned short* __restrict__ Bt,
    OutT* __restrict__ C,
    int M, int N, int K)
{
    __shared__ unsigned short As[128 * 32];
    __shared__ unsigned short Bs[128 * 32];
    int tiles_n = N >> 7;
    int tm = blockIdx.x / tiles_n, tn = blockIdx.x % tiles_n;
    int tid = threadIdx.x;
    int lane = tid & 63, wave = tid >> 6;
    int wr = wave >> 1, wc = wave & 1;
    int l15 = lane & 15, kh = lane >> 4;
    f32x4 acc[4][4] = {};
    int row0 = tm << 7, col0 = tn << 7;
    int srow = tid >> 2, scg = (tid & 3) << 3;
    const unsigned short* Abase = A + (size_t)(row0 + srow) * K + scg;
    const unsigned short* Bbase = Bt + (size_t)(col0 + srow) * K + scg;
    char* AsW = (char*)As + (wave << 10);
    char* BsW = (char*)Bs + (wave << 10);
    for (int k0 = 0; k0 < K; k0 += 32) {
        gload_lds16(Abase + k0, AsW);
        gload_lds16(Abase + (size_t)64 * K + k0, AsW + 4096);
        gload_lds16(Bbase + k0, BsW);
        gload_lds16(Bbase + (size_t)64 * K + k0, BsW + 4096);
        __syncthreads();
        short8 af[4], bfr[4];
        #pragma unroll
        for (int i = 0; i < 4; i++) af[i] = *(const short8*)(As + (wr * 64 + i * 16 + l15) * 32 + kh * 8);
        #pragma unroll
        for (int j = 0; j < 4; j++) bfr[j] = *(const short8*)(Bs + (wc * 64 + j * 16 + l15) * 32 + kh * 8);
        #pragma unroll
        for (int i = 0; i < 4; i++)
            #pragma unroll
            for (int j = 0; j < 4; j++)
                acc[i][j] = mfma16(af[i], bfr[j], acc[i][j]);
        __syncthreads();
    }
    #pragma unroll
    for (int i = 0; i < 4; i++)
        #pragma unroll
        for (int j = 0; j < 4; j++)
            #pragma unroll
            for (int r = 0; r < 4; r++) {
                int row = row0 + wr * 64 + i * 16 + kh * 4 + r;
                int col = col0 + wc * 64 + j * 16 + l15;
                float v = acc[i][j][r];
                if constexpr (sizeof(OutT) == 2) C[(size_t)row * N + col] = (OutT)f2bf(v);
                else                             C[(size_t)row * N + col] = v;
            }
}

// ---------------- RoPE on Q and K in place ----------------
__global__ void k_rope(unsigned short* __restrict__ Q, unsigned short* __restrict__ K) {
    int i = blockIdx.x * blockDim.x + threadIdx.x;  // quad index, grid exact
    int q4 = i & 15;
    int head = (i >> 4) & (NH - 1);
    int tok = i >> 9;
    int s = tok & (SL - 1);
    int d0 = q4 << 2;
    size_t base = (size_t)tok * HS + head * HD;
    float cs[4], sn[4];
    #pragma unroll
    for (int j = 0; j < 4; j++) {
        float invf = expf(-(float)(d0 + j) * 0.14391156831212787f);  // ln(1e4)/64
        float ang = (float)s * invf;
        sn[j] = sinf(ang); cs[j] = cosf(ang);
    }
    {
        u16x4 lo = *(u16x4*)(Q + base + d0);
        u16x4 hi = *(u16x4*)(Q + base + d0 + 64);
        u16x4 nlo, nhi;
        #pragma unroll
        for (int j = 0; j < 4; j++) {
            float x0 = bf2f(lo[j]), x1 = bf2f(hi[j]);
            nlo[j] = f2bf(x0 * cs[j] - x1 * sn[j]);
            nhi[j] = f2bf(x1 * cs[j] + x0 * sn[j]);
        }
        *(u16x4*)(Q + base + d0) = nlo;
        *(u16x4*)(Q + base + d0 + 64) = nhi;
    }
    {
        u16x4 lo = *(u16x4*)(K + base + d0);
        u16x4 hi = *(u16x4*)(K + base + d0 + 64);
        u16x4 nlo, nhi;
        #pragma unroll
        for (int j = 0; j < 4; j++) {
            float x0 = bf2f(lo[j]), x1 = bf2f(hi[j]);
            nlo[j] = f2bf(x0 * cs[j] - x1 * sn[j]);
            nhi[j] = f2bf(x1 * cs[j] + x0 * sn[j]);
        }
        *(u16x4*)(K + base + d0) = nlo;
        *(u16x4*)(K + base + d0 + 64) = nhi;
    }
}

// ---------------- V (tok, h*128+d) -> Vt ((b,h), d, s) ----------------
__global__ void k_transpose_v(const unsigned short* __restrict__ V, unsigned short* __restrict__ Vt) {
    __shared__ unsigned short t[32][36];
    int bh = blockIdx.z; int b = bh >> 5, h = bh & 31;
    int s0 = blockIdx.x << 5, d0 = blockIdx.y << 5;
    int tr = threadIdx.x >> 3, tc = (threadIdx.x & 7) << 2;
    u16x4 v = *(const u16x4*)(V + (size_t)(b * SL + s0 + tr) * HS + h * HD + d0 + tc);
    t[tr][tc + 0] = v[0]; t[tr][tc + 1] = v[1]; t[tr][tc + 2] = v[2]; t[tr][tc + 3] = v[3];
    __syncthreads();
    u16x4 o;
    o[0] = t[tc + 0][tr]; o[1] = t[tc + 1][tr]; o[2] = t[tc + 2][tr]; o[3] = t[tc + 3][tr];
    *(u16x4*)(Vt + ((size_t)(b * NH + h) * HD + d0 + tr) * SL + s0 + tc) = o;
}

// ---------------- causal flash attention ----------------
__global__ __launch_bounds__(256) void k_attn(
    const unsigned short* __restrict__ Q,
    const unsigned short* __restrict__ Kb,
    const unsigned short* __restrict__ Vt,
    unsigned short* __restrict__ O)
{
    __shared__ unsigned short Ks[64 * 128];   // [kk][d], chunk-swizzled
    __shared__ unsigned short Vs[128 * 64];   // [d][kk], chunk-swizzled
    __shared__ unsigned short Ps[4][16][72];  // per-wave P transpose, padded
    int qt = blockIdx.x;
    int bh = blockIdx.y;
    int b = bh >> 5, h = bh & 31;
    int tid = threadIdx.x, lane = tid & 63, wave = tid >> 6;
    int l15 = lane & 15, kh = lane >> 4;
    int qrow0 = (qt << 6) + (wave << 4);
    short8 qf[4];
    {
        const unsigned short* qp = Q + ((size_t)(b * SL) + qrow0 + l15) * HS + h * HD + kh * 8;
        #pragma unroll
        for (int f = 0; f < 4; ++f) qf[f] = *(const short8*)(qp + f * 32);
    }
    f32x4 oacc[8] = {};
    float m[4] = {-1e30f, -1e30f, -1e30f, -1e30f};
    float lsum[4] = {0.f, 0.f, 0.f, 0.f};
    const float scale = 0.08838834764831845f;  // 1/sqrt(128)
    int ksrow = tid >> 4, kchunk = tid & 15;
    int vsrow = tid >> 3, vchunk = tid & 7;
    const unsigned short* Kbase = Kb + (size_t)(b * SL) * HS + h * HD;
    const unsigned short* Vbase = Vt + (size_t)(b * NH + h) * HD * (size_t)SL;
    char* KsW = (char*)Ks + (wave << 10);
    char* VsW = (char*)Vs + (wave << 10);
    for (int kt = 0; kt <= qt; ++kt) {
        #pragma unroll
        for (int c = 0; c < 4; ++c) {
            int kr = c * 16 + ksrow;
            gload_lds16(Kbase + (size_t)((kt << 6) + kr) * HS + ((kchunk ^ (kr & 7)) << 3),
                        KsW + c * 4096);
            int vr = c * 32 + vsrow;
            gload_lds16(Vbase + (size_t)vr * SL + (kt << 6) + ((vchunk ^ (vr & 7)) << 3),
                        VsW + c * 4096);
        }
        __syncthreads();
        // S = Q K^T
        f32x4 sfr[4];
        #pragma unroll
        for (int c = 0; c < 4; ++c) {
            f32x4 acc = {};
            int krow = c * 16 + l15;
            #pragma unroll
            for (int f = 0; f < 4; ++f) {
                short8 kf = *(const short8*)((const char*)Ks + krow * 256 + ((((f << 2) + kh) ^ (krow & 7)) << 4));
                acc = mfma16(qf[f], kf, acc);
            }
            sfr[c] = acc;
        }
        // scale + causal mask + online softmax
        float pm[4] = {-1e30f, -1e30f, -1e30f, -1e30f};
        #pragma unroll
        for (int c = 0; c < 4; ++c) {
            int kkg = (kt << 6) + c * 16 + l15;
            #pragma unroll
            for (int r = 0; r < 4; ++r) {
                float v = sfr[c][r] * scale;
                int qg = qrow0 + kh * 4 + r;
                v = (kkg > qg) ? -1e30f : v;
                sfr[c][r] = v;
                pm[r] = fmaxf(pm[r], v);
            }
        }
        #pragma unroll
        for (int off = 1; off < 16; off <<= 1) {
            #pragma unroll
            for (int r = 0; r < 4; ++r) pm[r] = fmaxf(pm[r], __shfl_xor(pm[r], off, 64));
        }
        float alpha[4];
        #pragma unroll
        for (int r = 0; r < 4; ++r) {
            float mn = fmaxf(m[r], pm[r]);
            alpha[r] = __expf(m[r] - mn);
            m[r] = mn;
        }
        float rs[4] = {0.f, 0.f, 0.f, 0.f};
        #pragma unroll
        for (int c = 0; c < 4; ++c)
            #pragma unroll
            for (int r = 0; r < 4; ++r) {
                float p = __expf(sfr[c][r] - m[r]);
                sfr[c][r] = p;
                rs[r] += p;
            }
        #pragma unroll
        for (int off = 1; off < 16; off <<= 1) {
            #pragma unroll
            for (int r = 0; r < 4; ++r) rs[r] += __shfl_xor(rs[r], off, 64);
        }
        #pragma unroll
        for (int r = 0; r < 4; ++r) lsum[r] = lsum[r] * alpha[r] + rs[r];
        #pragma unroll
        for (int d = 0; d < 8; ++d)
            #pragma unroll
            for (int r = 0; r < 4; ++r) oacc[d][r] *= alpha[r];
        // P -> LDS (transpose to A-fragment layout)
        #pragma unroll
        for (int c = 0; c < 4; ++c)
            #pragma unroll
            for (int r = 0; r < 4; ++r)
                Ps[wave][kh * 4 + r][c * 16 + l15] = f2bf(sfr[c][r]);
        __syncthreads();
        short8 pa[2];
        pa[0] = *(const short8*)(&Ps[wave][l15][kh * 8]);
        pa[1] = *(const short8*)(&Ps[wave][l15][32 + kh * 8]);
        #pragma unroll
        for (int db = 0; db < 8; ++db) {
            int vrow = db * 16 + l15;
            #pragma unroll
            for (int f = 0; f < 2; ++f) {
                short8 vf = *(const short8*)((const char*)Vs + vrow * 128 + ((((f << 2) + kh) ^ (vrow & 7)) << 4));
                oacc[db] = mfma16(pa[f], vf, oacc[db]);
            }
        }
        __syncthreads();
    }
    #pragma unroll
    for (int db = 0; db < 8; ++db)
        #pragma unroll
        for (int r = 0; r < 4; ++r) {
            int qg = qrow0 + kh * 4 + r;
            float v = oacc[db][r] / lsum[r];
            O[((size_t)(b * SL) + qg) * HS + h * HD + db * 16 + l15] = f2bf(v);
        }
}

extern "C" void kernel_launch(void* const* d_in, const int* in_sizes, int n_in,
                              void* d_out, int out_size, void* d_ws, size_t ws_size,
                              hipStream_t stream)
{
    const float* X  = (const float*)d_in[0];
    const float* Wq = (const float*)d_in[1];
    const float* Wk = (const float*)d_in[2];
    const float* Wv = (const float*)d_in[3];
    const float* Wo = (const float*)d_in[4];
    float* out = (float*)d_out;
    const size_t SLAB = (size_t)NTOK * HS * 2;  // 32 MiB per bf16 slab
    char* ws = (char*)d_ws;
    unsigned short* Xb  = (unsigned short*)(ws + 0 * SLAB);
    unsigned short* Wqt = (unsigned short*)(ws + 1 * SLAB);
    unsigned short* Wkt = (unsigned short*)(ws + 2 * SLAB);
    unsigned short* Wvt = (unsigned short*)(ws + 3 * SLAB);
    unsigned short* Wot = (unsigned short*)(ws + 4 * SLAB);
    unsigned short* Qb  = (unsigned short*)(ws + 5 * SLAB);
    unsigned short* Kbb = (unsigned short*)(ws + 6 * SLAB);
    unsigned short* Vb  = (unsigned short*)(ws + 7 * SLAB);
    unsigned short* Vtb = Xb;   // alias: Xb dead after V projection
    unsigned short* Ob  = Wqt;  // alias: Wqt dead after Q projection

    k_convert<<<2048, 256, 0, stream>>>(X, Xb, NTOK * HS / 8);
    dim3 tg(128, 128);
    k_transpose_w<<<tg, 256, 0, stream>>>(Wq, Wqt);
    k_transpose_w<<<tg, 256, 0, stream>>>(Wk, Wkt);
    k_transpose_w<<<tg, 256, 0, stream>>>(Wv, Wvt);
    k_transpose_w<<<tg, 256, 0, stream>>>(Wo, Wot);
    k_gemm<unsigned short><<<1024, 256, 0, stream>>>(Xb, Wqt, Qb, NTOK, HS, HS);
    k_gemm<unsigned short><<<1024, 256, 0, stream>>>(Xb, Wkt, Kbb, NTOK, HS, HS);
    k_gemm<unsigned short><<<1024, 256, 0, stream>>>(Xb, Wvt, Vb, NTOK, HS, HS);
    k_rope<<<NTOK * NH * 16 / 256, 256, 0, stream>>>(Qb, Kbb);
    k_transpose_v<<<dim3(SL / 32, HD / 32, BS * NH), 256, 0, stream>>>(Vb, Vtb);
    k_attn<<<dim3(SL / 64, BS * NH), 256, 0, stream>>>(Qb, Kbb, Vtb, Ob);
    k_gemm<float><<<1024, 256, 0, stream>>>(Ob, Wot, out, NTOK, HS, HS);
}